// Round 20
// baseline (13868.898 us; speedup 1.0000x reference)
//
#include <hip/hip_runtime.h>
#include <hip/hip_bf16.h>
#include <type_traits>

// NeuralODE Bosh3 — Round 20: r18 (proven: 4.64ms, atomic per-panel sync,
// coalesced publish) + XCD-local DATA path only. Sync protocol is r18's
// device-scope atomic counters in BOTH modes (deadlock-free by construction).
// Exchange data switches to sc0-only (XCD-L2) iff: all 8 members report the
// same HW_REG_XCC_ID AND a bounded sc0 handshake succeeds (verdicts combined
// via device-scope atomics; no unbounded sc0 poll exists -> a wrong gate can
// only fail absmax, never hang). Fallback = exact r18 sc0sc1 path.

#define B_ 2048
#define L_ 128
#define P_ 8
#define T_ 128
#define GT_ 64
#define NGRP (B_/GT_)          // 32 groups
#define NBLK 256

typedef __attribute__((ext_vector_type(8))) short short8;
typedef __attribute__((ext_vector_type(4))) float f32x4;
typedef __attribute__((ext_vector_type(4))) unsigned int u32x4;

// wp layout (ushort units), weights member-major (100 frags per member)
#define WTOT (800*512)
#define CNT_OFF (WTOT + 256)            // sync counters + test/verdict slots
#define EXB (CNT_OFF + 16768)           // exchange buffers base
#define XSTR 160
#define GSTR (64*XSTR + 2*64*512)
#define NZERO 8320                      // u32s zeroed at CNT_OFF each launch

#define VMW0 asm volatile("s_waitcnt vmcnt(0)" ::: "memory")
#define LKW0 asm volatile("s_waitcnt lgkmcnt(0)" ::: "memory")
#define SCHB __builtin_amdgcn_sched_barrier(0)

__device__ __forceinline__ unsigned short f2bf(float f){
  unsigned u = __builtin_bit_cast(unsigned, f);
  u += 0x7fffu + ((u >> 16) & 1u);
  return (unsigned short)(u >> 16);
}

__device__ __forceinline__ float tanh_fast(float x){
  float e = __expf(2.0f * x);
  return 1.0f - __fdividef(2.0f, e + 1.0f);
}

template<bool COH> __device__ __forceinline__ short8 ld_ex(const unsigned short* p){
  u32x4 r;
  if constexpr (COH)
    asm volatile("global_load_dwordx4 %0, %1, off sc0" : "=v"(r) : "v"(p) : "memory");
  else
    asm volatile("global_load_dwordx4 %0, %1, off sc0 sc1" : "=v"(r) : "v"(p) : "memory");
  return __builtin_bit_cast(short8, r);
}
template<bool COH> __device__ __forceinline__ void st_ex16(unsigned short* p, u32x4 v){
  if constexpr (COH)
    asm volatile("global_store_dwordx4 %0, %1, off sc0" :: "v"(p), "v"(v) : "memory");
  else
    asm volatile("global_store_dwordx4 %0, %1, off sc0 sc1" :: "v"(p), "v"(v) : "memory");
}
__device__ __forceinline__ void st2_l3(unsigned short* p, unsigned short v){
  unsigned vv = v;
  asm volatile("global_store_short %0, %1, off sc0 sc1" :: "v"(p), "v"(vv) : "memory");
}

__global__ void prep_weights(const float* __restrict__ W0,
                             const float* __restrict__ W1,
                             const float* __restrict__ W2,
                             const float* __restrict__ ts,
                             unsigned short* __restrict__ wp){
  int idx = blockIdx.x * blockDim.x + threadIdx.x;
  if (idx >= WTOT){
    int t = idx - WTOT;
    if (t < T_ - 1){
      float* dts = (float*)(wp + WTOT);
      dts[t] = ts[t+1] - ts[t];
    } else if (t >= T_ && t < T_ + NZERO){
      ((unsigned*)(wp + CNT_OFF))[t - T_] = 0u;    // zeroed every launch
    }
    return;
  }
  int e = idx & 511, f = idx >> 9;
  int j = e & 7, lane = e >> 3;
  int m = f / 100, r = f % 100;
  const float* src; int nt, kt, Korig;
  if (r < 20)      { src = W0; Korig = 136; nt = 4*m + r/5;        kt = r%5; }
  else if (r < 84) { int q = r-20; src = W1; Korig = 512; nt = 4*m + (q>>4); kt = q&15; }
  else             { src = W2; Korig = 512; nt = m;                kt = r-84; }
  int row = nt*16 + (lane & 15);
  int k   = kt*32 + ((lane >> 4) << 3) + j;
  float v = (k < Korig) ? src[row*Korig + k] : 0.0f;
  wp[idx] = f2bf(v);
}

__global__ __launch_bounds__(256, 1)
void ode_main(const float* __restrict__ x0,
              const float* __restrict__ args,
              const float* __restrict__ b0, const float* __restrict__ b1,
              const float* __restrict__ b2,
              unsigned short* wp,
              float* __restrict__ out){
  __shared__ __align__(16) unsigned short wlds[100*512];   // 100 KiB
  __shared__ __align__(16) unsigned short hstg[4][16][64]; // 8 KiB stage
  __shared__ float dtl[T_];
  __shared__ unsigned cohsh;

  const int tid  = threadIdx.x;
  const int lane = tid & 63;
  const int wv   = tid >> 6;        // wave 0..3 = row panel
  const int lo   = lane & 15;
  const int hi   = lane >> 4;
  const int bid  = blockIdx.x;
  const int m    = bid >> 5;        // member 0..7; group members at bid%8==g%8
  const int g    = bid & 31;        // group 0..31 (XCD-local heuristic)
  const int r0   = g * GT_;

  unsigned* cnt = (unsigned*)(wp + CNT_OFF) + (g*4 + wv)*64;   // r18 spacing
  unsigned* tsl = (unsigned*)(wp + CNT_OFF) + 8192 + g;        // handshake slot
  unsigned* vc  = (unsigned*)(wp + CNT_OFF) + 8256 + g;        // verdict count
  unsigned short* gx  = wp + EXB + (size_t)g * GSTR;     // x [64][160]
  unsigned short* h1b = gx  + 64*XSTR;                   // h1 [64][512]
  unsigned short* h2b = h1b + 64*512;                    // h2 [64][512]

  // weights slice -> LDS (once)
  {
    const u32x4* s = (const u32x4*)(wp + (size_t)m * 51200);
    u32x4* d = (u32x4*)wlds;
    for (int i = tid; i < 6400; i += 256) d[i] = s[i];
  }
  if (tid < T_-1) dtl[tid] = ((const float*)(wp + WTOT))[tid];

  float b0v[4], b1v[4];
  #pragma unroll
  for (int n = 0; n < 4; ++n){
    b0v[n] = b0[(4*m + n)*16 + lo];
    b1v[n] = b1[(4*m + n)*16 + lo];
  }
  const int c3 = m*16 + lo;
  float b2v = b2[c3];

  unsigned xcc;
  asm volatile("s_getreg_b32 %0, hwreg(HW_REG_XCC_ID)" : "=s"(xcc));
  xcc &= 0xFu;

  // ODE state init + L3 publish (sc0sc1: visible to both modes)
  float yr[4], yn[4];
  #pragma unroll
  for (int j = 0; j < 4; ++j){
    int row = wv*16 + 4*hi + j;
    float v = x0[(r0 + row)*L_ + c3];
    yr[j] = v;
    __builtin_nontemporal_store(v, &out[((r0 + row)*T_ + 0)*L_ + c3]);
    st2_l3(gx + row*XSTR + c3, f2bf(v));
  }
  if (m == 0){
    #pragma unroll
    for (int e = 0; e < 8; ++e){
      int idx = lane*8 + e;
      int row = wv*16 + (idx >> 5), cc = 128 + (idx & 31);
      unsigned short vv = (cc < 136) ? f2bf(args[(r0 + row)*P_ + (cc - 128)])
                                     : (unsigned short)0;
      st2_l3(gx + row*XSTR + cc, vv);
    }
  }
  __syncthreads();   // wlds + dtl visible

  // init sync: r18 atomic sigpoll, phase target 8
  VMW0;
  if (lane == 0)
    __hip_atomic_fetch_add(cnt, 1u, __ATOMIC_RELAXED, __HIP_MEMORY_SCOPE_AGENT);
  {
    unsigned v;
    do {
      v = 0;
      if (lane == 0)
        v = __hip_atomic_load(cnt, __ATOMIC_RELAXED, __HIP_MEMORY_SCOPE_AGENT);
      v = __shfl(v, 0);
      if (v < 8) __builtin_amdgcn_s_sleep(1);
    } while (v < 8);
  }

  // XCD-coherence gate: bounded sc0 handshake + xcc match; verdicts via
  // device-scope atomics (no unbounded sc0 poll -> cannot hang).
  if (wv == 0){
    if (m == 0 && lane == 0){
      unsigned mg = 0xC0DE0000u | xcc;
      asm volatile("global_store_dword %0, %1, off sc0" :: "v"(tsl), "v"(mg) : "memory");
    }
    VMW0;
    unsigned v = 0;
    if (lane == 0){
      for (int it = 0; it < (1<<16); ++it){
        unsigned tv;
        asm volatile("global_load_dword %0, %1, off sc0" : "=v"(tv) : "v"(tsl) : "memory");
        VMW0;
        if (tv == (0xC0DE0000u | xcc)){ v = 1; break; }
        __builtin_amdgcn_s_sleep(2);
      }
      __hip_atomic_fetch_add(vc, 1u + (v << 8), __ATOMIC_RELAXED, __HIP_MEMORY_SCOPE_AGENT);
      unsigned c;
      do {
        c = __hip_atomic_load(vc, __ATOMIC_RELAXED, __HIP_MEMORY_SCOPE_AGENT);
        if ((c & 0xFFu) < 8) __builtin_amdgcn_s_sleep(2);
      } while ((c & 0xFFu) < 8);
      cohsh = ((c >> 8) == 8u);
    }
  }
  __syncthreads();
  const unsigned coh = cohsh;

  const int arow = wv*16 + lo;
  const int aoff = hi << 3;
  const int r16 = lane >> 2, ch4 = lane & 3;
  const int xr16 = (lane & 31) >> 1, xch = lane & 1;

  auto run = [&](auto coh_t){
    constexpr bool COH = decltype(coh_t)::value;
    unsigned tgt = 16;
    auto sigpoll = [&]{
      if (lane == 0)
        __hip_atomic_fetch_add(cnt, 1u, __ATOMIC_RELAXED, __HIP_MEMORY_SCOPE_AGENT);
      unsigned v;
      do {
        v = 0;
        if (lane == 0)
          v = __hip_atomic_load(cnt, __ATOMIC_RELAXED, __HIP_MEMORY_SCOPE_AGENT);
        v = __shfl(v, 0);
        if (v < tgt) __builtin_amdgcn_s_sleep(1);
      } while (v < tgt);
      tgt += 8;
    };

    auto publish_h = [&](unsigned short* hb){
      LKW0;
      u32x4 v0 = *(const u32x4*)&hstg[wv][r16][ch4*16];
      u32x4 v1 = *(const u32x4*)&hstg[wv][r16][ch4*16 + 8];
      unsigned short* dst = hb + (wv*16 + r16)*512 + m*64 + ch4*16;
      st_ex16<COH>(dst, v0);
      st_ex16<COH>(dst + 8, v1);
      VMW0;
    };

    auto phase1 = [&]{
      short8 xa[5];
      #pragma unroll
      for (int kt = 0; kt < 5; ++kt)
        xa[kt] = ld_ex<COH>(gx + arow*XSTR + kt*32 + aoff);
      VMW0; SCHB;
      f32x4 acc[4];
      #pragma unroll
      for (int n = 0; n < 4; ++n) acc[n] = f32x4{0,0,0,0};
      #pragma unroll
      for (int kt = 0; kt < 5; ++kt)
        #pragma unroll
        for (int n = 0; n < 4; ++n){
          short8 wf = *(const short8*)(wlds + (n*5 + kt)*512 + lane*8);
          acc[n] = __builtin_amdgcn_mfma_f32_16x16x32_bf16(xa[kt], wf, acc[n], 0, 0, 0);
        }
      #pragma unroll
      for (int n = 0; n < 4; ++n)
        #pragma unroll
        for (int j = 0; j < 4; ++j)
          hstg[wv][4*hi + j][n*16 + lo] = f2bf(tanh_fast(acc[n][j] + b0v[n]));
      publish_h(h1b);
      sigpoll();
    };

    auto phase2 = [&]{
      short8 ha[16];
      #pragma unroll
      for (int kt = 0; kt < 16; ++kt)
        ha[kt] = ld_ex<COH>(h1b + arow*512 + kt*32 + aoff);
      VMW0; SCHB;
      f32x4 acc[4];
      #pragma unroll
      for (int n = 0; n < 4; ++n) acc[n] = f32x4{0,0,0,0};
      #pragma unroll
      for (int kt = 0; kt < 16; ++kt)
        #pragma unroll
        for (int n = 0; n < 4; ++n){
          short8 wf = *(const short8*)(wlds + (20 + n*16 + kt)*512 + lane*8);
          acc[n] = __builtin_amdgcn_mfma_f32_16x16x32_bf16(ha[kt], wf, acc[n], 0, 0, 0);
        }
      #pragma unroll
      for (int n = 0; n < 4; ++n)
        #pragma unroll
        for (int j = 0; j < 4; ++j)
          hstg[wv][4*hi + j][n*16 + lo] = f2bf(tanh_fast(acc[n][j] + b1v[n]));
      publish_h(h2b);
      sigpoll();
    };

    for (int t = 1; t < T_; ++t){
      float dt = dtl[t-1];
      #pragma unroll 1
      for (int s = 0; s < 3; ++s){
        phase1();
        phase2();
        // phase3: layer 3 + state update + x publish
        short8 h2a[16];
        #pragma unroll
        for (int kt = 0; kt < 16; ++kt)
          h2a[kt] = ld_ex<COH>(h2b + arow*512 + kt*32 + aoff);
        VMW0; SCHB;
        f32x4 a3 = f32x4{0,0,0,0};
        #pragma unroll
        for (int kt = 0; kt < 16; ++kt){
          short8 wf = *(const short8*)(wlds + (84 + kt)*512 + lane*8);
          a3 = __builtin_amdgcn_mfma_f32_16x16x32_bf16(h2a[kt], wf, a3, 0, 0, 0);
        }
        #pragma unroll
        for (int j = 0; j < 4; ++j){
          float k = a3[j] + b2v;
          float xs;
          if (s == 0){ yn[j] = yr[j] + dt*(2.0f/9.0f)*k; xs = yr[j] + 0.5f*dt*k; }
          else if (s == 1){ yn[j] += dt*(1.0f/3.0f)*k;   xs = yr[j] + 0.75f*dt*k; }
          else { yn[j] += dt*(4.0f/9.0f)*k; yr[j] = yn[j]; xs = yr[j]; }
          hstg[wv][4*hi + j][lo] = f2bf(xs);
        }
        LKW0;
        if (lane < 32){   // coalesced x publish: 16 rows x 16 cols x 2B
          u32x4 v = *(const u32x4*)&hstg[wv][xr16][xch*8];
          st_ex16<COH>(gx + (wv*16 + xr16)*XSTR + m*16 + xch*8, v);
        }
        VMW0;
        if (lane == 0)
          __hip_atomic_fetch_add(cnt, 1u, __ATOMIC_RELAXED, __HIP_MEMORY_SCOPE_AGENT);
        if (s == 2){      // out store overlaps the poll
          #pragma unroll
          for (int j = 0; j < 4; ++j){
            int row = wv*16 + 4*hi + j;
            __builtin_nontemporal_store(yr[j], &out[((r0 + row)*T_ + t)*L_ + c3]);
          }
        }
        {
          unsigned v;
          do {
            v = 0;
            if (lane == 0)
              v = __hip_atomic_load(cnt, __ATOMIC_RELAXED, __HIP_MEMORY_SCOPE_AGENT);
            v = __shfl(v, 0);
            if (v < tgt) __builtin_amdgcn_s_sleep(1);
          } while (v < tgt);
          tgt += 8;
        }
      }
    }
  };

  if (coh) run(std::integral_constant<bool, true>{});
  else     run(std::integral_constant<bool, false>{});
}

extern "C" void kernel_launch(void* const* d_in, const int* in_sizes, int n_in,
                              void* d_out, int out_size, void* d_ws, size_t ws_size,
                              hipStream_t stream) {
  const float* x0   = (const float*)d_in[0];
  const float* ts   = (const float*)d_in[1];
  const float* args = (const float*)d_in[2];
  const float* W0   = (const float*)d_in[3];
  const float* b0   = (const float*)d_in[4];
  const float* W1   = (const float*)d_in[5];
  const float* b1   = (const float*)d_in[6];
  const float* W2   = (const float*)d_in[7];
  const float* b2   = (const float*)d_in[8];
  unsigned short* wp = (unsigned short*)d_ws;   // ~5.75 MB used
  float* out = (float*)d_out;

  prep_weights<<<(WTOT + T_ + NZERO + 255)/256, 256, 0, stream>>>(W0, W1, W2, ts, wp);
  ode_main<<<NBLK, 256, 0, stream>>>(x0, args, b0, b1, b2, wp, out);
}

// Round 21
// 4285.136 us; speedup vs baseline: 3.2365x; 3.2365x over previous
//
#include <hip/hip_runtime.h>
#include <hip/hip_bf16.h>
#include <type_traits>

// NeuralODE Bosh3 — Round 21: r18 core (atomic per-panel device-scope sync,
// coalesced publish) + DYNAMIC XCD-grouping: blocks register their measured
// HW_REG_XCC_ID; with 1 block/CU (103KB LDS) and grid=256=#CUs each XCD has
// exactly 32 blocks, so groups formed by (xcc, rank) are GUARANTEED
// co-located -> exchange data uses sc0 (XCD L2). Sync stays device-scope
// atomics (proven). No polls with timeouts; registration barrier is the
// same co-residency bet as r13-r18. Uneven counts -> exact r18 fallback.

#define B_ 2048
#define L_ 128
#define P_ 8
#define T_ 128
#define GT_ 64
#define NGRP (B_/GT_)          // 32 groups
#define NBLK 256

typedef __attribute__((ext_vector_type(8))) short short8;
typedef __attribute__((ext_vector_type(4))) float f32x4;
typedef __attribute__((ext_vector_type(4))) unsigned int u32x4;

// wp layout (ushort units), weights member-major (100 frags per member)
#define WTOT (800*512)
#define CNT_OFF (WTOT + 256)            // u32 area: 8192 sync + 16 reg/bar
#define EXB (CNT_OFF + 16448)           // exchange buffers base
#define XSTR 160
#define GSTR (64*XSTR + 2*64*512)
#define NZERO 8208                      // u32s zeroed at CNT_OFF each launch

#define VMW0 asm volatile("s_waitcnt vmcnt(0)" ::: "memory")
#define LKW0 asm volatile("s_waitcnt lgkmcnt(0)" ::: "memory")
#define SCHB __builtin_amdgcn_sched_barrier(0)

__device__ __forceinline__ unsigned short f2bf(float f){
  unsigned u = __builtin_bit_cast(unsigned, f);
  u += 0x7fffu + ((u >> 16) & 1u);
  return (unsigned short)(u >> 16);
}

__device__ __forceinline__ float tanh_fast(float x){
  float e = __expf(2.0f * x);
  return 1.0f - __fdividef(2.0f, e + 1.0f);
}

template<bool COH> __device__ __forceinline__ short8 ld_ex(const unsigned short* p){
  u32x4 r;
  if constexpr (COH)
    asm volatile("global_load_dwordx4 %0, %1, off sc0" : "=v"(r) : "v"(p) : "memory");
  else
    asm volatile("global_load_dwordx4 %0, %1, off sc0 sc1" : "=v"(r) : "v"(p) : "memory");
  return __builtin_bit_cast(short8, r);
}
template<bool COH> __device__ __forceinline__ void st_ex16(unsigned short* p, u32x4 v){
  if constexpr (COH)
    asm volatile("global_store_dwordx4 %0, %1, off sc0" :: "v"(p), "v"(v) : "memory");
  else
    asm volatile("global_store_dwordx4 %0, %1, off sc0 sc1" :: "v"(p), "v"(v) : "memory");
}
__device__ __forceinline__ void st2_l3(unsigned short* p, unsigned short v){
  unsigned vv = v;
  asm volatile("global_store_short %0, %1, off sc0 sc1" :: "v"(p), "v"(vv) : "memory");
}

__global__ void prep_weights(const float* __restrict__ W0,
                             const float* __restrict__ W1,
                             const float* __restrict__ W2,
                             const float* __restrict__ ts,
                             unsigned short* __restrict__ wp){
  int idx = blockIdx.x * blockDim.x + threadIdx.x;
  if (idx >= WTOT){
    int t = idx - WTOT;
    if (t < T_ - 1){
      float* dts = (float*)(wp + WTOT);
      dts[t] = ts[t+1] - ts[t];
    } else if (t >= T_ && t < T_ + NZERO){
      ((unsigned*)(wp + CNT_OFF))[t - T_] = 0u;    // zeroed every launch
    }
    return;
  }
  int e = idx & 511, f = idx >> 9;
  int j = e & 7, lane = e >> 3;
  int m = f / 100, r = f % 100;
  const float* src; int nt, kt, Korig;
  if (r < 20)      { src = W0; Korig = 136; nt = 4*m + r/5;        kt = r%5; }
  else if (r < 84) { int q = r-20; src = W1; Korig = 512; nt = 4*m + (q>>4); kt = q&15; }
  else             { src = W2; Korig = 512; nt = m;                kt = r-84; }
  int row = nt*16 + (lane & 15);
  int k   = kt*32 + ((lane >> 4) << 3) + j;
  float v = (k < Korig) ? src[row*Korig + k] : 0.0f;
  wp[idx] = f2bf(v);
}

__global__ __launch_bounds__(256, 1)
void ode_main(const float* __restrict__ x0,
              const float* __restrict__ args,
              const float* __restrict__ b0, const float* __restrict__ b1,
              const float* __restrict__ b2,
              unsigned short* wp,
              float* __restrict__ out){
  __shared__ __align__(16) unsigned short wlds[100*512];   // 100 KiB
  __shared__ __align__(16) unsigned short hstg[4][16][64]; // 8 KiB stage
  __shared__ float dtl[T_];
  __shared__ unsigned sh_rank, sh_ok, sh_xcc;

  const int tid  = threadIdx.x;
  const int lane = tid & 63;
  const int wv   = tid >> 6;        // wave 0..3 = row panel
  const int lo   = lane & 15;
  const int hi   = lane >> 4;
  const int bid  = blockIdx.x;

  unsigned* syncbase = (unsigned*)(wp + CNT_OFF);

  if (tid < T_-1) dtl[tid] = ((const float*)(wp + WTOT))[tid];

  // ---- dynamic XCD-group registration (device-scope atomics; the bar poll
  // is bounded by co-residency: 1 block/CU, grid = #CUs)
  if (tid == 0){
    unsigned xcc;
    asm volatile("s_getreg_b32 %0, hwreg(HW_REG_XCC_ID)" : "=s"(xcc));
    xcc &= 7u;
    unsigned* reg = syncbase + 8192;
    unsigned* bar = syncbase + 8200;
    unsigned rank = __hip_atomic_fetch_add(&reg[xcc], 1u, __ATOMIC_RELAXED, __HIP_MEMORY_SCOPE_AGENT);
    __hip_atomic_fetch_add(bar, 1u, __ATOMIC_RELAXED, __HIP_MEMORY_SCOPE_AGENT);
    while (__hip_atomic_load(bar, __ATOMIC_RELAXED, __HIP_MEMORY_SCOPE_AGENT) < 256u)
      __builtin_amdgcn_s_sleep(2);
    unsigned ok = 1;
    #pragma unroll
    for (int i = 0; i < 8; ++i)
      ok &= (__hip_atomic_load(&reg[i], __ATOMIC_RELAXED, __HIP_MEMORY_SCOPE_AGENT) == 32u);
    sh_rank = rank; sh_ok = ok; sh_xcc = xcc;
  }
  __syncthreads();
  const unsigned ok = sh_ok;
  const int m = ok ? (int)(sh_rank & 7u) : (bid >> 5);
  const int g = ok ? (int)(sh_xcc*4u + (sh_rank >> 3)) : (bid & 31);
  const int r0 = g * GT_;

  unsigned* cnt = syncbase + (g*4 + wv)*64;
  unsigned short* gx  = wp + EXB + (size_t)g * GSTR;     // x [64][160]
  unsigned short* h1b = gx  + 64*XSTR;                   // h1 [64][512]
  unsigned short* h2b = h1b + 64*512;                    // h2 [64][512]

  // weights slice -> LDS (once; m now known)
  {
    const u32x4* s = (const u32x4*)(wp + (size_t)m * 51200);
    u32x4* d = (u32x4*)wlds;
    for (int i = tid; i < 6400; i += 256) d[i] = s[i];
  }

  float b0v[4], b1v[4];
  #pragma unroll
  for (int n = 0; n < 4; ++n){
    b0v[n] = b0[(4*m + n)*16 + lo];
    b1v[n] = b1[(4*m + n)*16 + lo];
  }
  const int c3 = m*16 + lo;
  float b2v = b2[c3];

  // ODE state init + publish at device point (visible to both modes)
  float yr[4], yn[4];
  #pragma unroll
  for (int j = 0; j < 4; ++j){
    int row = wv*16 + 4*hi + j;
    float v = x0[(r0 + row)*L_ + c3];
    yr[j] = v;
    __builtin_nontemporal_store(v, &out[((r0 + row)*T_ + 0)*L_ + c3]);
    st2_l3(gx + row*XSTR + c3, f2bf(v));
  }
  if (m == 0){
    #pragma unroll
    for (int e = 0; e < 8; ++e){
      int idx = lane*8 + e;
      int row = wv*16 + (idx >> 5), cc = 128 + (idx & 31);
      unsigned short vv = (cc < 136) ? f2bf(args[(r0 + row)*P_ + (cc - 128)])
                                     : (unsigned short)0;
      st2_l3(gx + row*XSTR + cc, vv);
    }
  }
  __syncthreads();   // wlds visible

  // init sync (r18 atomic sigpoll, target 8)
  VMW0;
  if (lane == 0)
    __hip_atomic_fetch_add(cnt, 1u, __ATOMIC_RELAXED, __HIP_MEMORY_SCOPE_AGENT);
  {
    unsigned v;
    do {
      v = 0;
      if (lane == 0)
        v = __hip_atomic_load(cnt, __ATOMIC_RELAXED, __HIP_MEMORY_SCOPE_AGENT);
      v = __shfl(v, 0);
      if (v < 8) __builtin_amdgcn_s_sleep(1);
    } while (v < 8);
  }

  const int arow = wv*16 + lo;
  const int aoff = hi << 3;
  const int r16 = lane >> 2, ch4 = lane & 3;
  const int xr16 = (lane & 31) >> 1, xch = lane & 1;

  auto run = [&](auto coh_t){
    constexpr bool COH = decltype(coh_t)::value;
    unsigned tgt = 16;
    auto sigpoll = [&]{
      if (lane == 0)
        __hip_atomic_fetch_add(cnt, 1u, __ATOMIC_RELAXED, __HIP_MEMORY_SCOPE_AGENT);
      unsigned v;
      do {
        v = 0;
        if (lane == 0)
          v = __hip_atomic_load(cnt, __ATOMIC_RELAXED, __HIP_MEMORY_SCOPE_AGENT);
        v = __shfl(v, 0);
        if (v < tgt) __builtin_amdgcn_s_sleep(1);
      } while (v < tgt);
      tgt += 8;
    };

    auto publish_h = [&](unsigned short* hb){
      LKW0;
      u32x4 v0 = *(const u32x4*)&hstg[wv][r16][ch4*16];
      u32x4 v1 = *(const u32x4*)&hstg[wv][r16][ch4*16 + 8];
      unsigned short* dst = hb + (wv*16 + r16)*512 + m*64 + ch4*16;
      st_ex16<COH>(dst, v0);
      st_ex16<COH>(dst + 8, v1);
      VMW0;
    };

    auto phase1 = [&]{
      short8 xa[5];
      #pragma unroll
      for (int kt = 0; kt < 5; ++kt)
        xa[kt] = ld_ex<COH>(gx + arow*XSTR + kt*32 + aoff);
      VMW0; SCHB;
      f32x4 acc[4];
      #pragma unroll
      for (int n = 0; n < 4; ++n) acc[n] = f32x4{0,0,0,0};
      #pragma unroll
      for (int kt = 0; kt < 5; ++kt)
        #pragma unroll
        for (int n = 0; n < 4; ++n){
          short8 wf = *(const short8*)(wlds + (n*5 + kt)*512 + lane*8);
          acc[n] = __builtin_amdgcn_mfma_f32_16x16x32_bf16(xa[kt], wf, acc[n], 0, 0, 0);
        }
      #pragma unroll
      for (int n = 0; n < 4; ++n)
        #pragma unroll
        for (int j = 0; j < 4; ++j)
          hstg[wv][4*hi + j][n*16 + lo] = f2bf(tanh_fast(acc[n][j] + b0v[n]));
      publish_h(h1b);
      sigpoll();
    };

    auto phase2 = [&]{
      short8 ha[16];
      #pragma unroll
      for (int kt = 0; kt < 16; ++kt)
        ha[kt] = ld_ex<COH>(h1b + arow*512 + kt*32 + aoff);
      VMW0; SCHB;
      f32x4 acc[4];
      #pragma unroll
      for (int n = 0; n < 4; ++n) acc[n] = f32x4{0,0,0,0};
      #pragma unroll
      for (int kt = 0; kt < 16; ++kt)
        #pragma unroll
        for (int n = 0; n < 4; ++n){
          short8 wf = *(const short8*)(wlds + (20 + n*16 + kt)*512 + lane*8);
          acc[n] = __builtin_amdgcn_mfma_f32_16x16x32_bf16(ha[kt], wf, acc[n], 0, 0, 0);
        }
      #pragma unroll
      for (int n = 0; n < 4; ++n)
        #pragma unroll
        for (int j = 0; j < 4; ++j)
          hstg[wv][4*hi + j][n*16 + lo] = f2bf(tanh_fast(acc[n][j] + b1v[n]));
      publish_h(h2b);
      sigpoll();
    };

    for (int t = 1; t < T_; ++t){
      float dt = dtl[t-1];
      #pragma unroll 1
      for (int s = 0; s < 3; ++s){
        phase1();
        phase2();
        // phase3: layer 3 + state update + x publish
        short8 h2a[16];
        #pragma unroll
        for (int kt = 0; kt < 16; ++kt)
          h2a[kt] = ld_ex<COH>(h2b + arow*512 + kt*32 + aoff);
        VMW0; SCHB;
        f32x4 a3 = f32x4{0,0,0,0};
        #pragma unroll
        for (int kt = 0; kt < 16; ++kt){
          short8 wf = *(const short8*)(wlds + (84 + kt)*512 + lane*8);
          a3 = __builtin_amdgcn_mfma_f32_16x16x32_bf16(h2a[kt], wf, a3, 0, 0, 0);
        }
        #pragma unroll
        for (int j = 0; j < 4; ++j){
          float k = a3[j] + b2v;
          float xs;
          if (s == 0){ yn[j] = yr[j] + dt*(2.0f/9.0f)*k; xs = yr[j] + 0.5f*dt*k; }
          else if (s == 1){ yn[j] += dt*(1.0f/3.0f)*k;   xs = yr[j] + 0.75f*dt*k; }
          else { yn[j] += dt*(4.0f/9.0f)*k; yr[j] = yn[j]; xs = yr[j]; }
          hstg[wv][4*hi + j][lo] = f2bf(xs);
        }
        LKW0;
        if (lane < 32){   // coalesced x publish: 16 rows x 16 cols x 2B
          u32x4 v = *(const u32x4*)&hstg[wv][xr16][xch*8];
          st_ex16<COH>(gx + (wv*16 + xr16)*XSTR + m*16 + xch*8, v);
        }
        VMW0;
        if (lane == 0)
          __hip_atomic_fetch_add(cnt, 1u, __ATOMIC_RELAXED, __HIP_MEMORY_SCOPE_AGENT);
        if (s == 2){      // out store overlaps the poll
          #pragma unroll
          for (int j = 0; j < 4; ++j){
            int row = wv*16 + 4*hi + j;
            __builtin_nontemporal_store(yr[j], &out[((r0 + row)*T_ + t)*L_ + c3]);
          }
        }
        {
          unsigned v;
          do {
            v = 0;
            if (lane == 0)
              v = __hip_atomic_load(cnt, __ATOMIC_RELAXED, __HIP_MEMORY_SCOPE_AGENT);
            v = __shfl(v, 0);
            if (v < tgt) __builtin_amdgcn_s_sleep(1);
          } while (v < tgt);
          tgt += 8;
        }
      }
    }
  };

  if (ok) run(std::integral_constant<bool, true>{});
  else    run(std::integral_constant<bool, false>{});
}

extern "C" void kernel_launch(void* const* d_in, const int* in_sizes, int n_in,
                              void* d_out, int out_size, void* d_ws, size_t ws_size,
                              hipStream_t stream) {
  const float* x0   = (const float*)d_in[0];
  const float* ts   = (const float*)d_in[1];
  const float* args = (const float*)d_in[2];
  const float* W0   = (const float*)d_in[3];
  const float* b0   = (const float*)d_in[4];
  const float* W1   = (const float*)d_in[5];
  const float* b1   = (const float*)d_in[6];
  const float* W2   = (const float*)d_in[7];
  const float* b2   = (const float*)d_in[8];
  unsigned short* wp = (unsigned short*)d_ws;   // ~5.75 MB used
  float* out = (float*)d_out;

  prep_weights<<<(WTOT + T_ + NZERO + 255)/256, 256, 0, stream>>>(W0, W1, W2, ts, wp);
  ode_main<<<NBLK, 256, 0, stream>>>(x0, args, b0, b1, b2, wp, out);
}